// Round 5
// baseline (101.134 us; speedup 1.0000x reference)
//
#include <hip/hip_runtime.h>

#ifndef B_GRAPHS
#define B_GRAPHS 512
#endif

#define ROWS_PER_GROUP 4

typedef float f32x4 __attribute__((ext_vector_type(4)));

// Kernel 1: boundary-detection offsets (bv is SORTED).
// offs[b] = lower_bound(bv, b). Thread i fills (bv[i-1], bv[i]]; thread n-1
// also fills the tail. One coalesced pass, no dependent chains, no atomics.
__global__ void boundary_offsets_kernel(const int* __restrict__ bv, int n,
                                        int num_graphs, int* __restrict__ offs) {
    int i = blockIdx.x * blockDim.x + threadIdx.x;
    if (i >= n) return;
    int cur  = bv[i];
    int prev = (i == 0) ? -1 : bv[i - 1];
    for (int b = prev + 1; b <= cur; ++b) offs[b] = i;
    if (i == n - 1) {
        for (int b = cur + 1; b <= num_graphs; ++b) offs[b] = n;
    }
}

// Kernel 2: gather-formulated unbatch+pad (R4 main streams unchanged).
// grid.y = graph b (offs loads wave-uniform). Each 32-lane group handles
// ROWS_PER_GROUP consecutive rows; lane moves one float4/row (D=128).
// R5 change: side streams coalesced — lanes 0-3 load 4 consecutive y and
// store 4 consecutive tgt (one transaction each); lanes 4-7 store msk.
// Replaces lane0/lane1 divergent 4-iteration scalar loops.
__global__ void gather_pad_kernel(const f32x4* __restrict__ vals4,
                                  const int* __restrict__ y,
                                  const int* __restrict__ offs,
                                  f32x4* __restrict__ enc4,
                                  float* __restrict__ tgt,
                                  float* __restrict__ msk,
                                  int max_len) {
    const int b     = blockIdx.y;
    const int start = offs[b];           // uniform -> s_load
    const int size  = offs[b + 1] - start;

    const int group = threadIdx.x >> 5;
    const int lane  = threadIdx.x & 31;
    const int groups_per_block = blockDim.x >> 5;
    const int pos0 = (blockIdx.x * groups_per_block + group) * ROWS_PER_GROUP;

    f32x4 v[ROWS_PER_GROUP];
    #pragma unroll
    for (int r = 0; r < ROWS_PER_GROUP; ++r) {
        int pos = pos0 + r;
        f32x4 z = {0.f, 0.f, 0.f, 0.f};
        v[r] = z;
        if (pos < size)
            v[r] = __builtin_nontemporal_load(&vals4[(size_t)(start + pos) * 32 + lane]);
    }

    const size_t rowbase = (size_t)b * max_len + pos0;
    #pragma unroll
    for (int r = 0; r < ROWS_PER_GROUP; ++r) {
        int pos = pos0 + r;
        if (pos < max_len)
            __builtin_nontemporal_store(v[r], &enc4[(rowbase + r) * 32 + lane]);
    }

    // Side streams: one predicated step, coalesced within the group.
    if (lane < 8) {
        int sl  = lane & 3;              // row within the group
        int pos = pos0 + sl;
        if (pos < max_len) {
            bool valid = pos < size;
            if (lane < 4) {
                tgt[rowbase + sl] = valid ? (float)y[start + pos] : 0.0f;
            } else {
                msk[rowbase + sl] = valid ? 1.0f : 0.0f;
            }
        }
    }
}

extern "C" void kernel_launch(void* const* d_in, const int* in_sizes, int n_in,
                              void* d_out, int out_size, void* d_ws, size_t ws_size,
                              hipStream_t stream) {
    const float* values = (const float*)d_in[0];
    const int*   y      = (const int*)d_in[1];
    const int*   bv     = (const int*)d_in[2];

    const int N = in_sizes[1];            // 500000 nodes
    const int D = in_sizes[0] / N;        // 128
    const int B = B_GRAPHS;               // 512 (compile-time in reference)
    const int max_len = out_size / (B * (D + 2));
    const int total_rows = B * max_len;

    int* offs = (int*)d_ws;               // B+1 ints

    {
        int threads = 256;
        int blocks = (N + threads - 1) / threads;
        boundary_offsets_kernel<<<blocks, threads, 0, stream>>>(bv, N, B, offs);
    }

    {
        f32x4* enc4 = (f32x4*)d_out;
        float* tgt  = (float*)d_out + (size_t)total_rows * D;
        float* msk  = (float*)d_out + (size_t)total_rows * (D + 1);
        int threads = 256;                                    // 8 groups/block
        int rows_per_block = (threads >> 5) * ROWS_PER_GROUP; // 32 rows
        dim3 grid((max_len + rows_per_block - 1) / rows_per_block, B, 1);
        gather_pad_kernel<<<grid, threads, 0, stream>>>(
            (const f32x4*)values, y, offs, enc4, tgt, msk, max_len);
    }
}